// Round 8
// baseline (91.928 us; speedup 1.0000x reference)
//
#include <hip/hip_runtime.h>
#include <hip/hip_bf16.h>

#define NSPK 1024
#define MU 32
#define DIM 512
#define DIMP (DIM + 8)
#define NROW (NSPK * MU)   // 32768
#define EPS 1e-6f

typedef __attribute__((ext_vector_type(4))) float f32x4;
typedef __attribute__((ext_vector_type(8))) short bf16x8;

#define GLOAD_LDS16(g, l)                                          \
  __builtin_amdgcn_global_load_lds(                                \
      (const __attribute__((address_space(1))) void*)(g),          \
      (__attribute__((address_space(3))) void*)(l), 16, 0, 0)

__device__ inline ushort f2bf(float x) {
  __hip_bfloat16 h = __float2bfloat16(x);
  return *reinterpret_cast<ushort*>(&h);
}

// ---------------------------------------------------------------------------
// Kernel 1: per-speaker prep. LOO cosines (fp32 exact) + normalized bf16
// A and B written in MFMA-FRAGMENT-MAJOR layout:
//   frag(rb,kf) [A] / frag(nb,kf) [B] = 512 ushorts; lane l holds
//   row/col = base16 + (l&15), k = kf*32 + (l>>4)*8 .. +8   (16 B chunk)
// grid = NSPK, block = 256
// ---------------------------------------------------------------------------
__global__ __launch_bounds__(256) void k_prep(
    const float* __restrict__ dvecs,
    ushort* __restrict__ Af,    // [2048 rb][16 kf][64 lane][8]
    ushort* __restrict__ Bf,    // [64 nb][16 kf][64 lane][8]
    float* __restrict__ loo)    // [NROW]
{
  const int j = blockIdx.x, t = threadIdx.x;
  __shared__ float sD[MU * DIMP];   // padded raw speaker rows (66.5 KiB)
  __shared__ float sS[DIM];
  __shared__ float sred[4];
  __shared__ float sS2v;
  __shared__ float sInv[MU];

  const float* base = dvecs + (size_t)j * (MU * DIM);

  // single global read: stage rows + column sums
  float s0 = 0.f, s1 = 0.f;
  for (int m = 0; m < MU; ++m) {
    float a = base[m * DIM + t];
    float b = base[m * DIM + t + 256];
    sD[m * DIMP + t] = a;
    sD[m * DIMP + t + 256] = b;
    s0 += a; s1 += b;
  }
  sS[t] = s0; sS[t + 256] = s1;
  __syncthreads();

  // |S|^2
  float p = s0 * s0 + s1 * s1;
  for (int off = 32; off; off >>= 1) p += __shfl_down(p, off);
  if ((t & 63) == 0) sred[t >> 6] = p;
  __syncthreads();
  if (t == 0) sS2v = sred[0] + sred[1] + sred[2] + sred[3];
  __syncthreads();
  const float S2 = sS2v;

  // per-utterance dot(e,S), |e|^2 from LDS (8 lanes per row)
  const int g = t >> 3, l = t & 7;
  float dotS = 0.f, e2 = 0.f;
  for (int i = 0; i < DIM / 8; ++i) {
    int d = i * 8 + l;
    float ev = sD[g * DIMP + d];
    dotS += ev * sS[d];
    e2 += ev * ev;
  }
  for (int off = 4; off; off >>= 1) {
    dotS += __shfl_down(dotS, off);
    e2 += __shfl_down(e2, off);
  }
  if (l == 0) {
    float numer = dotS - e2;                          // e.(S-e)
    float d2 = fmaxf(S2 - 2.f * dotS + e2, 1e-30f);   // |S-e|^2
    loo[j * MU + g] = numer / (sqrtf(e2) * sqrtf(d2));
    sInv[g] = 1.f / sqrtf(e2);
  }
  __syncthreads();

  // A fragments: this speaker = rows j*32..+31 = rb j*2, j*2+1
  for (int i = 0; i < 8; ++i) {
    int idx = i * 256 + t;          // 0..2047 16B-chunks
    int fragL = idx >> 6;           // 0..31 (rbl*16 + kf)
    int lane2 = idx & 63;
    int rbl = fragL >> 4, kf = fragL & 15;
    int m = rbl * 16 + (lane2 & 15);
    int k0 = kf * 32 + (lane2 >> 4) * 8;
    float inv = sInv[m];
    ushort tmp[8];
#pragma unroll
    for (int z = 0; z < 8; ++z) tmp[z] = f2bf(sD[m * DIMP + k0 + z] * inv);
    *(bf16x8*)&Af[(((size_t)(j * 2 + rbl) * 16 + kf) << 9) + lane2 * 8] =
        *(bf16x8*)tmp;
  }

  // B fragment pieces for centroid j (col j -> lane&15 = j&15)
  if (t < 64) {
    int kf = t >> 2, q = t & 3;
    int lane2 = q * 16 + (j & 15);
    float invc = 1.f / sqrtf(S2);
    int k0 = kf * 32 + q * 8;
    ushort tmp[8];
#pragma unroll
    for (int z = 0; z < 8; ++z) tmp[z] = f2bf(sS[k0 + z] * invc);
    *(bf16x8*)&Bf[(((size_t)(j >> 4) * 16 + kf) << 9) + lane2 * 8] =
        *(bf16x8*)tmp;
  }
}

// ---------------------------------------------------------------------------
// Kernel 2: barrier-free fused cosine-GEMM.
// One block = 64 rows x ALL 1024 cols, 256 threads (4 waves); grid = 512.
// R7 post-mortem: acc[4][8] (128 regs) + 236 arch VGPR ~= 360/512 of the
// unified pool -> 1 wave/SIMD -> nothing hides B's L2 latency (Occupancy
// 10%, MfmaUtil 24%). This round: acc[4][4] over 4 col-sub-chunks halves
// the live accumulator -> ~2 waves/SIMD + register headroom for the
// compiler to prefetch B a kf ahead. A-frag ds_reads double (2 MiB/CU
// ~10us, still under the 16.5us MFMA floor, co-scheduled). s_setprio(1)
// around the MFMA cluster: waves are independent (no barrier in the
// K-loop), the regime where priority arbitration measured +4-7%.
// grid = 512, block = 256
// ---------------------------------------------------------------------------
__global__ __launch_bounds__(256, 1) void k_gemm(
    const ushort* __restrict__ Af,
    const ushort* __restrict__ Bf,
    const float* __restrict__ wp,
    float* __restrict__ part,    // [NROW] sum of exp over all 1024 cols
    float* __restrict__ diag)    // [NROW] raw cos vs own full centroid
{
  __shared__ ushort ldsA[64 * DIM];    // 64 KiB, fragment-linear
  __shared__ float sPart[64][4];

  const int t = threadIdx.x;
  const int w = t >> 6, lane = t & 63;
  const int lr = lane & 15, lk = lane >> 4;
  const int rblk = blockIdx.x;         // 0..511
  const float W = *wp;

  // stage A panel once: 64 frags x 1 KiB, linear global_load_lds
  {
    const ushort* gsrc = Af + (size_t)rblk * (64 * DIM);
    const int off = t * 8;   // ushort units, lane-contiguous 16B
#pragma unroll
    for (int i = 0; i < 16; ++i)
      GLOAD_LDS16(gsrc + off + i * 2048, ((char*)ldsA) + (off + i * 2048) * 2);
  }
  __syncthreads();   // only barrier before epilogue

  float sum[4][4];
#pragma unroll
  for (int a = 0; a < 4; ++a)
#pragma unroll
    for (int b = 0; b < 4; ++b) sum[a][b] = 0.f;

#pragma unroll
  for (int sub = 0; sub < 4; ++sub) {
    f32x4 acc[4][4];
#pragma unroll
    for (int a = 0; a < 4; ++a)
#pragma unroll
      for (int b = 0; b < 4; ++b) acc[a][b] = (f32x4)0.f;

    // this sub-chunk's 4 B fragments; frag nb stride = 8192 ushorts (<<13)
    const ushort* bp0 = Bf + ((size_t)(w * 16 + sub * 4) << 13) + lane * 8;

#pragma unroll
    for (int kf = 0; kf < 16; ++kf) {
      bf16x8 bfr[4];
#pragma unroll
      for (int nf = 0; nf < 4; ++nf)
        bfr[nf] = *(const bf16x8*)(bp0 + (size_t)((nf * 16 + kf) << 9));
      __builtin_amdgcn_s_setprio(1);
#pragma unroll
      for (int mf = 0; mf < 4; ++mf) {
        const bf16x8 afr =
            *(const bf16x8*)&ldsA[((mf * 16 + kf) << 9) + lane * 8];
#pragma unroll
        for (int nf = 0; nf < 4; ++nf)
          acc[mf][nf] = __builtin_amdgcn_mfma_f32_16x16x32_bf16(
              afr, bfr[nf], acc[mf][nf], 0, 0, 0);
      }
      __builtin_amdgcn_s_setprio(0);
    }

    // fused epilogue: exp((fmax(cos,eps)-1)*W)  [shift w+b cancels in lse]
#pragma unroll
    for (int mf = 0; mf < 4; ++mf)
#pragma unroll
      for (int i = 0; i < 4; ++i) {
#pragma unroll
        for (int nf = 0; nf < 4; ++nf)
          sum[mf][i] += __expf((fmaxf(acc[mf][nf][i], EPS) - 1.f) * W);
      }

    // diag capture: block's 2 speakers c = rblk*2 + sp; col c lives in
    // wave w = c>>8, sub = (c>>6)&3, nf = (c>>4)&3, lanes lr == c&15;
    // its rows are mf = sp*2 + mh (mh=0,1).
#pragma unroll
    for (int sp = 0; sp < 2; ++sp) {
      const int c = rblk * 2 + sp;
      if (w == (c >> 8) && sub == ((c >> 6) & 3)) {
        const int nfo = (c >> 4) & 3;
#pragma unroll
        for (int mh = 0; mh < 2; ++mh) {
          f32x4 dsel = acc[sp * 2 + mh][0];
#pragma unroll
          for (int nf = 1; nf < 4; ++nf)
            if (nf == nfo) dsel = acc[sp * 2 + mh][nf];   // static idx only
          if (lr == (c & 15)) {
#pragma unroll
            for (int i = 0; i < 4; ++i)
              diag[rblk * 64 + (sp * 2 + mh) * 16 + lk * 4 + i] = dsel[i];
          }
        }
      }
    }
  }

  // reduce each row-sum across the 16 lr-lanes
#pragma unroll
  for (int mf = 0; mf < 4; ++mf)
#pragma unroll
    for (int i = 0; i < 4; ++i) {
      float v = sum[mf][i];
      v += __shfl_xor(v, 1);
      v += __shfl_xor(v, 2);
      v += __shfl_xor(v, 4);
      v += __shfl_xor(v, 8);
      sum[mf][i] = v;
    }
  if (lr == 0) {
#pragma unroll
    for (int mf = 0; mf < 4; ++mf)
#pragma unroll
      for (int i = 0; i < 4; ++i)
        sPart[mf * 16 + lk * 4 + i][w] = sum[mf][i];
  }
  __syncthreads();
  if (t < 64)
    part[rblk * 64 + t] =
        sPart[t][0] + sPart[t][1] + sPart[t][2] + sPart[t][3];
}

// ---------------------------------------------------------------------------
// Final: swap exp(diag)->exp(loo), close logsumexp, deterministic 2-stage sum
// L_row = log(part - exp(dt) + exp(lt)) - lt,  x_t = (fmax(x,eps)-1)*W
// ---------------------------------------------------------------------------
__global__ __launch_bounds__(256) void k_final1(
    const float* __restrict__ part, const float* __restrict__ loo,
    const float* __restrict__ diag, const float* __restrict__ wp,
    float* __restrict__ p2)
{
  const int t = threadIdx.x;
  const int r = blockIdx.x * 256 + t;
  const float W = *wp;
  const float lt = (fmaxf(loo[r], EPS) - 1.f) * W;
  const float dt = (fmaxf(diag[r], EPS) - 1.f) * W;
  const float s = part[r] + __expf(lt) - __expf(dt);
  float v = logf(s) - lt;
  __shared__ float red[4];
  for (int off = 32; off; off >>= 1) v += __shfl_down(v, off);
  if ((t & 63) == 0) red[t >> 6] = v;
  __syncthreads();
  if (t == 0) p2[blockIdx.x] = red[0] + red[1] + red[2] + red[3];
}

__global__ __launch_bounds__(128) void k_final2(
    const float* __restrict__ p2, float* __restrict__ out)
{
  const int t = threadIdx.x;
  float v = p2[t];
  for (int off = 32; off; off >>= 1) v += __shfl_down(v, off);
  __shared__ float red[2];
  if ((t & 63) == 0) red[t >> 6] = v;
  __syncthreads();
  if (t == 0) out[0] = red[0] + red[1];
}

extern "C" void kernel_launch(void* const* d_in, const int* in_sizes, int n_in,
                              void* d_out, int out_size, void* d_ws, size_t ws_size,
                              hipStream_t stream) {
  const float* dvecs = (const float*)d_in[0];
  const float* wptr  = (const float*)d_in[1];
  // b cancels algebraically (shift = w+b subtracted and re-added) -> unused
  float* out = (float*)d_out;

  char* ws = (char*)d_ws;
  ushort* Af = (ushort*)ws;  ws += (size_t)NROW * DIM * sizeof(ushort); // 32 MiB
  ushort* Bf = (ushort*)ws;  ws += (size_t)NSPK * DIM * sizeof(ushort); // 1 MiB
  float* loo  = (float*)ws;  ws += (size_t)NROW * sizeof(float);
  float* diag = (float*)ws;  ws += (size_t)NROW * sizeof(float);
  float* part = (float*)ws;  ws += (size_t)NROW * sizeof(float);
  float* p2   = (float*)ws;

  k_prep<<<NSPK, 256, 0, stream>>>(dvecs, Af, Bf, loo);
  k_gemm<<<512, 256, 0, stream>>>(Af, Bf, wptr, part, diag);
  k_final1<<<NROW / 256, 256, 0, stream>>>(part, loo, diag, wptr, p2);
  k_final2<<<1, 128, 0, stream>>>(p2, out);
}

// Round 10
// 76.390 us; speedup vs baseline: 1.2034x; 1.2034x over previous
//
#include <hip/hip_runtime.h>
#include <hip/hip_bf16.h>

#define NSPK 1024
#define MU 32
#define DIM 512
#define DIMP (DIM + 8)
#define NROW (NSPK * MU)   // 32768
#define EPS 1e-6f

typedef __attribute__((ext_vector_type(4))) float f32x4;
typedef __attribute__((ext_vector_type(8))) short bf16x8;

#define GLOAD_LDS16(g, l)                                          \
  __builtin_amdgcn_global_load_lds(                                \
      (const __attribute__((address_space(1))) void*)(g),          \
      (__attribute__((address_space(3))) void*)(l), 16, 0, 0)

__device__ inline ushort f2bf(float x) {
  __hip_bfloat16 h = __float2bfloat16(x);
  return *reinterpret_cast<ushort*>(&h);
}

// ---------------------------------------------------------------------------
// Kernel 1: per-speaker prep. LOO cosines (fp32 exact) + normalized bf16
// A and B written in MFMA-FRAGMENT-MAJOR layout:
//   frag(rb16,kf) [A] / frag(nb16,kf) [B] = 512 ushorts; lane l holds
//   row/col = base16 + (l&15), k = kf*32 + (l>>4)*8 .. +8   (16 B chunk)
// grid = NSPK, block = 256   (unchanged since R2; verified)
// ---------------------------------------------------------------------------
__global__ __launch_bounds__(256) void k_prep(
    const float* __restrict__ dvecs,
    ushort* __restrict__ Af,    // [2048 rb16][16 kf][64 lane][8]
    ushort* __restrict__ Bf,    // [64 nb16][16 kf][64 lane][8]
    float* __restrict__ loo)    // [NROW]
{
  const int j = blockIdx.x, t = threadIdx.x;
  __shared__ float sD[MU * DIMP];   // padded raw speaker rows (66.5 KiB)
  __shared__ float sS[DIM];
  __shared__ float sred[4];
  __shared__ float sS2v;
  __shared__ float sInv[MU];

  const float* base = dvecs + (size_t)j * (MU * DIM);

  // single global read: stage rows + column sums
  float s0 = 0.f, s1 = 0.f;
  for (int m = 0; m < MU; ++m) {
    float a = base[m * DIM + t];
    float b = base[m * DIM + t + 256];
    sD[m * DIMP + t] = a;
    sD[m * DIMP + t + 256] = b;
    s0 += a; s1 += b;
  }
  sS[t] = s0; sS[t + 256] = s1;
  __syncthreads();

  // |S|^2
  float p = s0 * s0 + s1 * s1;
  for (int off = 32; off; off >>= 1) p += __shfl_down(p, off);
  if ((t & 63) == 0) sred[t >> 6] = p;
  __syncthreads();
  if (t == 0) sS2v = sred[0] + sred[1] + sred[2] + sred[3];
  __syncthreads();
  const float S2 = sS2v;

  // per-utterance dot(e,S), |e|^2 from LDS (8 lanes per row)
  const int g = t >> 3, l = t & 7;
  float dotS = 0.f, e2 = 0.f;
  for (int i = 0; i < DIM / 8; ++i) {
    int d = i * 8 + l;
    float ev = sD[g * DIMP + d];
    dotS += ev * sS[d];
    e2 += ev * ev;
  }
  for (int off = 4; off; off >>= 1) {
    dotS += __shfl_down(dotS, off);
    e2 += __shfl_down(e2, off);
  }
  if (l == 0) {
    float numer = dotS - e2;                          // e.(S-e)
    float d2 = fmaxf(S2 - 2.f * dotS + e2, 1e-30f);   // |S-e|^2
    loo[j * MU + g] = numer / (sqrtf(e2) * sqrtf(d2));
    sInv[g] = 1.f / sqrtf(e2);
  }
  __syncthreads();

  // A fragments: this speaker = rows j*32..+31 = rb16 j*2, j*2+1
  for (int i = 0; i < 8; ++i) {
    int idx = i * 256 + t;          // 0..2047 16B-chunks
    int fragL = idx >> 6;           // 0..31 (rbl*16 + kf)
    int lane2 = idx & 63;
    int rbl = fragL >> 4, kf = fragL & 15;
    int m = rbl * 16 + (lane2 & 15);
    int k0 = kf * 32 + (lane2 >> 4) * 8;
    float inv = sInv[m];
    ushort tmp[8];
#pragma unroll
    for (int z = 0; z < 8; ++z) tmp[z] = f2bf(sD[m * DIMP + k0 + z] * inv);
    *(bf16x8*)&Af[(((size_t)(j * 2 + rbl) * 16 + kf) << 9) + lane2 * 8] =
        *(bf16x8*)tmp;
  }

  // B fragment pieces for centroid j (col j -> lane&15 = j&15)
  if (t < 64) {
    int kf = t >> 2, q = t & 3;
    int lane2 = q * 16 + (j & 15);
    float invc = 1.f / sqrtf(S2);
    int k0 = kf * 32 + q * 8;
    ushort tmp[8];
#pragma unroll
    for (int z = 0; z < 8; ++z) tmp[z] = f2bf(sS[k0 + z] * invc);
    *(bf16x8*)&Bf[(((size_t)(j >> 4) * 16 + kf) << 9) + lane2 * 8] =
        *(bf16x8*)tmp;
  }
}

// ---------------------------------------------------------------------------
// Kernel 2: double-buffered tiled GEMM, fused exp-sum epilogue.
// Tile 128x128, BK=64, 256 thr (4 waves, 2wm x 2wn), wave tile 64x64
// (acc[4][4] = 64 regs; live set ~170 -> no spill, ~2 waves/SIMD).
// LDS: 2 x (A 16K + B 16K) + sPart 1K = 65 KiB -> 2 blocks/CU.
// R4/R5/R9 lesson: 512-thr blocks pin 128 arch-VGPRs and spill; stay 256.
// R9 lesson: part[] had 4 writers per row -> race; now part[cb][NROW].
// Grid 2048 = 256 rb x 8 cb, XCD-chunked swizzle: each XCD owns a 32-rb
// band, cb varies fastest -> working set (8 A-panels + full B) ~2 MiB < L2.
// 2-phase K-loop: issue next-tile stage, compute current, one barrier/step.
// ---------------------------------------------------------------------------
__global__ __launch_bounds__(256, 1) void k_gemm(
    const ushort* __restrict__ Af,
    const ushort* __restrict__ Bf,
    const float* __restrict__ wp,
    float* __restrict__ part,    // [8][NROW] partial sumexp per col-chunk
    float* __restrict__ diag)    // [NROW] raw cos vs own full centroid
{
  __shared__ ushort ldsA[2 * 16 * 512];   // 32 KiB: 2 bufs x 16 frags x 1 KiB
  __shared__ ushort ldsB[2 * 16 * 512];   // 32 KiB
  __shared__ float sPart[128][2];         // 1 KiB

  const int t = threadIdx.x;
  const int w = t >> 6, lane = t & 63;
  const int lr = lane & 15, lk = lane >> 4;
  const int wm = w >> 1, wn = w & 1;      // 2 x 2 wave grid
  // XCD-chunked block swizzle (HW: consecutive bids round-robin XCDs)
  const int bid = blockIdx.x;
  const int xcd = bid & 7, ii = bid >> 3;     // ii in [0,256) per XCD
  const int rb = xcd * 32 + (ii >> 3);        // 0..255 (128 rows each)
  const int cb = ii & 7;                      // 0..7   (128 cols each)
  const float W = *wp;

  f32x4 acc[4][4];
#pragma unroll
  for (int a = 0; a < 4; ++a)
#pragma unroll
    for (int b = 0; b < 4; ++b) acc[a][b] = (f32x4)0.f;

  // staging: 16 frags each for A,B per K-step; wave w stages frags w,4+w,..
#define STAGE(kt, bi)                                                        \
  {                                                                          \
    _Pragma("unroll")                                                        \
    for (int r = 0; r < 4; ++r) {                                            \
      const int fi = r * 4 + w;              /* 0..15 */                     \
      const int el = fi >> 1, kfh = fi & 1;                                  \
      GLOAD_LDS16(                                                           \
          Af + (((size_t)(rb * 8 + el) * 16 + (kt) * 2 + kfh) << 9) +        \
              lane * 8,                                                      \
          &ldsA[(bi) * 8192 + fi * 512 + lane * 8]);                         \
      GLOAD_LDS16(                                                           \
          Bf + (((size_t)(cb * 8 + el) * 16 + (kt) * 2 + kfh) << 9) +        \
              lane * 8,                                                      \
          &ldsB[(bi) * 8192 + fi * 512 + lane * 8]);                         \
    }                                                                        \
  }

  STAGE(0, 0);
  __syncthreads();

  int cur = 0;
  for (int kt = 0; kt < 8; ++kt) {
    if (kt < 7) STAGE(kt + 1, cur ^ 1);

    const ushort* lA = &ldsA[cur * 8192];
    const ushort* lB = &ldsB[cur * 8192];
#pragma unroll
    for (int h = 0; h < 2; ++h) {
      bf16x8 bfr[4];
#pragma unroll
      for (int nf = 0; nf < 4; ++nf)
        bfr[nf] =
            *(const bf16x8*)&lB[(((wn * 4 + nf) * 2 + h) << 9) + lane * 8];
#pragma unroll
      for (int mf = 0; mf < 4; ++mf) {
        const bf16x8 afr =
            *(const bf16x8*)&lA[(((wm * 4 + mf) * 2 + h) << 9) + lane * 8];
#pragma unroll
        for (int nf = 0; nf < 4; ++nf)
          acc[mf][nf] = __builtin_amdgcn_mfma_f32_16x16x32_bf16(
              afr, bfr[nf], acc[mf][nf], 0, 0, 0);
      }
    }
    __syncthreads();   // drains stage vmcnt; protects buffer reuse
    cur ^= 1;
  }
#undef STAGE

  // ---- diag capture (raw cos) before exp consumes acc ----
  // block rows = speakers rb*4..+3; col c = rb*4+sp in this block iff
  // cb == c>>7 (= rb>>5, no carry since sp<4).
  if (cb == (rb >> 5)) {
#pragma unroll
    for (int sp = 0; sp < 4; ++sp) {
      const int c = rb * 4 + sp;
      if (wm == (sp >> 1) && wn == ((c >> 6) & 1)) {
        const int nfo = (c >> 4) & 3;
#pragma unroll
        for (int mh = 0; mh < 2; ++mh) {
          f32x4 dsel = acc[(sp & 1) * 2 + mh][0];
#pragma unroll
          for (int nf = 1; nf < 4; ++nf)
            if (nf == nfo) dsel = acc[(sp & 1) * 2 + mh][nf];  // static idx
          if (lr == (c & 15)) {
#pragma unroll
            for (int i = 0; i < 4; ++i)
              diag[c * 32 + mh * 16 + lk * 4 + i] = dsel[i];
          }
        }
      }
    }
  }

  // ---- fused epilogue: exp((fmax(cos,eps)-1)*W), reduce over 64 cols ----
#pragma unroll
  for (int mf = 0; mf < 4; ++mf)
#pragma unroll
    for (int i = 0; i < 4; ++i) {
      float s = 0.f;
#pragma unroll
      for (int nf = 0; nf < 4; ++nf)
        s += __expf((fmaxf(acc[mf][nf][i], EPS) - 1.f) * W);
      s += __shfl_xor(s, 1);
      s += __shfl_xor(s, 2);
      s += __shfl_xor(s, 4);
      s += __shfl_xor(s, 8);
      if (lr == 0) sPart[wm * 64 + mf * 16 + lk * 4 + i][wn] = s;
    }
  __syncthreads();
  if (t < 128)
    part[(size_t)cb * NROW + rb * 128 + t] = sPart[t][0] + sPart[t][1];
}

// ---------------------------------------------------------------------------
// Final: sum 8 col-chunk partials, swap exp(diag)->exp(loo), close lse,
// deterministic 2-stage sum.  L_row = log(s - exp(dt) + exp(lt)) - lt
// ---------------------------------------------------------------------------
__global__ __launch_bounds__(256) void k_final1(
    const float* __restrict__ part, const float* __restrict__ loo,
    const float* __restrict__ diag, const float* __restrict__ wp,
    float* __restrict__ p2)
{
  const int t = threadIdx.x;
  const int r = blockIdx.x * 256 + t;
  const float W = *wp;
  float s = 0.f;
#pragma unroll
  for (int c = 0; c < 8; ++c) s += part[(size_t)c * NROW + r];
  const float lt = (fmaxf(loo[r], EPS) - 1.f) * W;
  const float dt = (fmaxf(diag[r], EPS) - 1.f) * W;
  s += __expf(lt) - __expf(dt);
  float v = logf(s) - lt;
  __shared__ float red[4];
  for (int off = 32; off; off >>= 1) v += __shfl_down(v, off);
  if ((t & 63) == 0) red[t >> 6] = v;
  __syncthreads();
  if (t == 0) p2[blockIdx.x] = red[0] + red[1] + red[2] + red[3];
}

__global__ __launch_bounds__(128) void k_final2(
    const float* __restrict__ p2, float* __restrict__ out)
{
  const int t = threadIdx.x;
  float v = p2[t];
  for (int off = 32; off; off >>= 1) v += __shfl_down(v, off);
  __shared__ float red[2];
  if ((t & 63) == 0) red[t >> 6] = v;
  __syncthreads();
  if (t == 0) out[0] = red[0] + red[1];
}

extern "C" void kernel_launch(void* const* d_in, const int* in_sizes, int n_in,
                              void* d_out, int out_size, void* d_ws, size_t ws_size,
                              hipStream_t stream) {
  const float* dvecs = (const float*)d_in[0];
  const float* wptr  = (const float*)d_in[1];
  // b cancels algebraically (shift = w+b subtracted and re-added) -> unused
  float* out = (float*)d_out;

  char* ws = (char*)d_ws;
  ushort* Af = (ushort*)ws;  ws += (size_t)NROW * DIM * sizeof(ushort); // 32 MiB
  ushort* Bf = (ushort*)ws;  ws += (size_t)NSPK * DIM * sizeof(ushort); // 1 MiB
  float* loo  = (float*)ws;  ws += (size_t)NROW * sizeof(float);
  float* diag = (float*)ws;  ws += (size_t)NROW * sizeof(float);
  float* part = (float*)ws;  ws += (size_t)8 * NROW * sizeof(float);    // 1 MiB
  float* p2   = (float*)ws;

  k_prep<<<NSPK, 256, 0, stream>>>(dvecs, Af, Bf, loo);
  k_gemm<<<2048, 256, 0, stream>>>(Af, Bf, wptr, part, diag);
  k_final1<<<NROW / 256, 256, 0, stream>>>(part, loo, diag, wptr, p2);
  k_final2<<<1, 128, 0, stream>>>(p2, out);
}

// Round 11
// 76.064 us; speedup vs baseline: 1.2086x; 1.0043x over previous
//
#include <hip/hip_runtime.h>
#include <hip/hip_bf16.h>

#define NSPK 1024
#define MU 32
#define DIM 512
#define DIMP (DIM + 8)
#define NROW (NSPK * MU)   // 32768
#define EPS 1e-6f

typedef __attribute__((ext_vector_type(4))) float f32x4;
typedef __attribute__((ext_vector_type(8))) short bf16x8;

#define GLOAD_LDS16(g, l)                                          \
  __builtin_amdgcn_global_load_lds(                                \
      (const __attribute__((address_space(1))) void*)(g),          \
      (__attribute__((address_space(3))) void*)(l), 16, 0, 0)

__device__ inline ushort f2bf(float x) {
  __hip_bfloat16 h = __float2bfloat16(x);
  return *reinterpret_cast<ushort*>(&h);
}

// ---------------------------------------------------------------------------
// Kernel 1: per-speaker prep. LOO cosines (fp32 exact) + normalized bf16
// A and B written in MFMA-FRAGMENT-MAJOR layout:
//   frag(rb16,kf) [A] / frag(nb16,kf) [B] = 512 ushorts; lane l holds
//   row/col = base16 + (l&15), k = kf*32 + (l>>4)*8 .. +8   (16 B chunk)
// grid = NSPK, block = 256   (unchanged since R2; verified)
// ---------------------------------------------------------------------------
__global__ __launch_bounds__(256) void k_prep(
    const float* __restrict__ dvecs,
    ushort* __restrict__ Af,    // [2048 rb16][16 kf][64 lane][8]
    ushort* __restrict__ Bf,    // [64 nb16][16 kf][64 lane][8]
    float* __restrict__ loo)    // [NROW]
{
  const int j = blockIdx.x, t = threadIdx.x;
  __shared__ float sD[MU * DIMP];   // padded raw speaker rows (66.5 KiB)
  __shared__ float sS[DIM];
  __shared__ float sred[4];
  __shared__ float sS2v;
  __shared__ float sInv[MU];

  const float* base = dvecs + (size_t)j * (MU * DIM);

  // single global read: stage rows + column sums
  float s0 = 0.f, s1 = 0.f;
  for (int m = 0; m < MU; ++m) {
    float a = base[m * DIM + t];
    float b = base[m * DIM + t + 256];
    sD[m * DIMP + t] = a;
    sD[m * DIMP + t + 256] = b;
    s0 += a; s1 += b;
  }
  sS[t] = s0; sS[t + 256] = s1;
  __syncthreads();

  // |S|^2
  float p = s0 * s0 + s1 * s1;
  for (int off = 32; off; off >>= 1) p += __shfl_down(p, off);
  if ((t & 63) == 0) sred[t >> 6] = p;
  __syncthreads();
  if (t == 0) sS2v = sred[0] + sred[1] + sred[2] + sred[3];
  __syncthreads();
  const float S2 = sS2v;

  // per-utterance dot(e,S), |e|^2 from LDS (8 lanes per row)
  const int g = t >> 3, l = t & 7;
  float dotS = 0.f, e2 = 0.f;
  for (int i = 0; i < DIM / 8; ++i) {
    int d = i * 8 + l;
    float ev = sD[g * DIMP + d];
    dotS += ev * sS[d];
    e2 += ev * ev;
  }
  for (int off = 4; off; off >>= 1) {
    dotS += __shfl_down(dotS, off);
    e2 += __shfl_down(e2, off);
  }
  if (l == 0) {
    float numer = dotS - e2;                          // e.(S-e)
    float d2 = fmaxf(S2 - 2.f * dotS + e2, 1e-30f);   // |S-e|^2
    loo[j * MU + g] = numer / (sqrtf(e2) * sqrtf(d2));
    sInv[g] = 1.f / sqrtf(e2);
  }
  __syncthreads();

  // A fragments: this speaker = rows j*32..+31 = rb16 j*2, j*2+1
  for (int i = 0; i < 8; ++i) {
    int idx = i * 256 + t;          // 0..2047 16B-chunks
    int fragL = idx >> 6;           // 0..31 (rbl*16 + kf)
    int lane2 = idx & 63;
    int rbl = fragL >> 4, kf = fragL & 15;
    int m = rbl * 16 + (lane2 & 15);
    int k0 = kf * 32 + (lane2 >> 4) * 8;
    float inv = sInv[m];
    ushort tmp[8];
#pragma unroll
    for (int z = 0; z < 8; ++z) tmp[z] = f2bf(sD[m * DIMP + k0 + z] * inv);
    *(bf16x8*)&Af[(((size_t)(j * 2 + rbl) * 16 + kf) << 9) + lane2 * 8] =
        *(bf16x8*)tmp;
  }

  // B fragment pieces for centroid j (col j -> lane&15 = j&15)
  if (t < 64) {
    int kf = t >> 2, q = t & 3;
    int lane2 = q * 16 + (j & 15);
    float invc = 1.f / sqrtf(S2);
    int k0 = kf * 32 + q * 8;
    ushort tmp[8];
#pragma unroll
    for (int z = 0; z < 8; ++z) tmp[z] = f2bf(sS[k0 + z] * invc);
    *(bf16x8*)&Bf[(((size_t)(j >> 4) * 16 + kf) << 9) + lane2 * 8] =
        *(bf16x8*)tmp;
  }
}

// ---------------------------------------------------------------------------
// Kernel 2: double-buffered tiled GEMM, fused exp-sum epilogue.
// Tile 128x128, BK=32 (16 K-steps), 256 thr (4 waves, 2wm x 2wn), wave
// tile 64x64 (acc[4][4] = 64 AGPR + ~90 arch).
// R10 post-mortem: identical structure at BK=64 (65 KiB LDS) capped at
// 2 blocks/CU = 2 waves/SIMD and plateaued at 58us with every per-step
// vmcnt(0)+barrier drain exposed. BK=32 halves LDS to 33 KiB -> 3-4
// blocks/CU (12+ waves/CU, m97's occupancy regime) so co-resident blocks
// cover each other's drains. Staging traffic unchanged (512 MB ~ 15us at
// L2 ceiling, overlappable); LDS reads unchanged; barriers double but are
// now hidden. R4/R5/R9 lesson: stay at 256-thr blocks.
// Grid 2048 = 256 rb x 8 cb, XCD-chunked swizzle (32-rb band per XCD).
// ---------------------------------------------------------------------------
__global__ __launch_bounds__(256, 1) void k_gemm(
    const ushort* __restrict__ Af,
    const ushort* __restrict__ Bf,
    const float* __restrict__ wp,
    float* __restrict__ part,    // [8][NROW] partial sumexp per col-chunk
    float* __restrict__ diag)    // [NROW] raw cos vs own full centroid
{
  __shared__ ushort ldsA[2 * 8 * 512];    // 16 KiB: 2 bufs x 8 frags x 1 KiB
  __shared__ ushort ldsB[2 * 8 * 512];    // 16 KiB
  __shared__ float sPart[128][2];         // 1 KiB

  const int t = threadIdx.x;
  const int w = t >> 6, lane = t & 63;
  const int lr = lane & 15, lk = lane >> 4;
  const int wm = w >> 1, wn = w & 1;      // 2 x 2 wave grid
  // XCD-chunked block swizzle (HW: consecutive bids round-robin XCDs)
  const int bid = blockIdx.x;
  const int xcd = bid & 7, ii = bid >> 3;     // ii in [0,256) per XCD
  const int rb = xcd * 32 + (ii >> 3);        // 0..255 (128 rows each)
  const int cb = ii & 7;                      // 0..7   (128 cols each)
  const float W = *wp;

  f32x4 acc[4][4];
#pragma unroll
  for (int a = 0; a < 4; ++a)
#pragma unroll
    for (int b = 0; b < 4; ++b) acc[a][b] = (f32x4)0.f;

  // staging: 8 A-frags + 8 B-frags per K-step (BK=32 -> kf = kt directly);
  // wave w stages A el {w, w+4} and B el {w, w+4}.
#define STAGE(kt, bi)                                                        \
  {                                                                          \
    _Pragma("unroll")                                                        \
    for (int r = 0; r < 2; ++r) {                                            \
      const int el = r * 4 + w;              /* 0..7 */                      \
      GLOAD_LDS16(                                                           \
          Af + (((size_t)(rb * 8 + el) * 16 + (kt)) << 9) + lane * 8,        \
          &ldsA[(bi) * 4096 + el * 512 + lane * 8]);                         \
      GLOAD_LDS16(                                                           \
          Bf + (((size_t)(cb * 8 + el) * 16 + (kt)) << 9) + lane * 8,        \
          &ldsB[(bi) * 4096 + el * 512 + lane * 8]);                         \
    }                                                                        \
  }

  STAGE(0, 0);
  __syncthreads();

  int cur = 0;
  for (int kt = 0; kt < 16; ++kt) {
    if (kt < 15) STAGE(kt + 1, cur ^ 1);

    const ushort* lA = &ldsA[cur * 4096];
    const ushort* lB = &ldsB[cur * 4096];
    bf16x8 bfr[4];
#pragma unroll
    for (int nf = 0; nf < 4; ++nf)
      bfr[nf] = *(const bf16x8*)&lB[((wn * 4 + nf) << 9) + lane * 8];
#pragma unroll
    for (int mf = 0; mf < 4; ++mf) {
      const bf16x8 afr =
          *(const bf16x8*)&lA[((wm * 4 + mf) << 9) + lane * 8];
#pragma unroll
      for (int nf = 0; nf < 4; ++nf)
        acc[mf][nf] = __builtin_amdgcn_mfma_f32_16x16x32_bf16(
            afr, bfr[nf], acc[mf][nf], 0, 0, 0);
    }
    __syncthreads();   // drains stage vmcnt; protects buffer reuse
    cur ^= 1;
  }
#undef STAGE

  // ---- diag capture (raw cos) before exp consumes acc ----
  // block rows = speakers rb*4..+3; col c = rb*4+sp in this block iff
  // cb == c>>7 (= rb>>5, no carry since sp<4).
  if (cb == (rb >> 5)) {
#pragma unroll
    for (int sp = 0; sp < 4; ++sp) {
      const int c = rb * 4 + sp;
      if (wm == (sp >> 1) && wn == ((c >> 6) & 1)) {
        const int nfo = (c >> 4) & 3;
#pragma unroll
        for (int mh = 0; mh < 2; ++mh) {
          f32x4 dsel = acc[(sp & 1) * 2 + mh][0];
#pragma unroll
          for (int nf = 1; nf < 4; ++nf)
            if (nf == nfo) dsel = acc[(sp & 1) * 2 + mh][nf];  // static idx
          if (lr == (c & 15)) {
#pragma unroll
            for (int i = 0; i < 4; ++i)
              diag[c * 32 + mh * 16 + lk * 4 + i] = dsel[i];
          }
        }
      }
    }
  }

  // ---- fused epilogue: exp((fmax(cos,eps)-1)*W), reduce over 64 cols ----
#pragma unroll
  for (int mf = 0; mf < 4; ++mf)
#pragma unroll
    for (int i = 0; i < 4; ++i) {
      float s = 0.f;
#pragma unroll
      for (int nf = 0; nf < 4; ++nf)
        s += __expf((fmaxf(acc[mf][nf][i], EPS) - 1.f) * W);
      s += __shfl_xor(s, 1);
      s += __shfl_xor(s, 2);
      s += __shfl_xor(s, 4);
      s += __shfl_xor(s, 8);
      if (lr == 0) sPart[wm * 64 + mf * 16 + lk * 4 + i][wn] = s;
    }
  __syncthreads();
  if (t < 128)
    part[(size_t)cb * NROW + rb * 128 + t] = sPart[t][0] + sPart[t][1];
}

// ---------------------------------------------------------------------------
// Final: sum 8 col-chunk partials, swap exp(diag)->exp(loo), close lse,
// deterministic 2-stage sum.  L_row = log(s - exp(dt) + exp(lt)) - lt
// ---------------------------------------------------------------------------
__global__ __launch_bounds__(256) void k_final1(
    const float* __restrict__ part, const float* __restrict__ loo,
    const float* __restrict__ diag, const float* __restrict__ wp,
    float* __restrict__ p2)
{
  const int t = threadIdx.x;
  const int r = blockIdx.x * 256 + t;
  const float W = *wp;
  float s = 0.f;
#pragma unroll
  for (int c = 0; c < 8; ++c) s += part[(size_t)c * NROW + r];
  const float lt = (fmaxf(loo[r], EPS) - 1.f) * W;
  const float dt = (fmaxf(diag[r], EPS) - 1.f) * W;
  s += __expf(lt) - __expf(dt);
  float v = logf(s) - lt;
  __shared__ float red[4];
  for (int off = 32; off; off >>= 1) v += __shfl_down(v, off);
  if ((t & 63) == 0) red[t >> 6] = v;
  __syncthreads();
  if (t == 0) p2[blockIdx.x] = red[0] + red[1] + red[2] + red[3];
}

__global__ __launch_bounds__(128) void k_final2(
    const float* __restrict__ p2, float* __restrict__ out)
{
  const int t = threadIdx.x;
  float v = p2[t];
  for (int off = 32; off; off >>= 1) v += __shfl_down(v, off);
  __shared__ float red[2];
  if ((t & 63) == 0) red[t >> 6] = v;
  __syncthreads();
  if (t == 0) out[0] = red[0] + red[1];
}

extern "C" void kernel_launch(void* const* d_in, const int* in_sizes, int n_in,
                              void* d_out, int out_size, void* d_ws, size_t ws_size,
                              hipStream_t stream) {
  const float* dvecs = (const float*)d_in[0];
  const float* wptr  = (const float*)d_in[1];
  // b cancels algebraically (shift = w+b subtracted and re-added) -> unused
  float* out = (float*)d_out;

  char* ws = (char*)d_ws;
  ushort* Af = (ushort*)ws;  ws += (size_t)NROW * DIM * sizeof(ushort); // 32 MiB
  ushort* Bf = (ushort*)ws;  ws += (size_t)NSPK * DIM * sizeof(ushort); // 1 MiB
  float* loo  = (float*)ws;  ws += (size_t)NROW * sizeof(float);
  float* diag = (float*)ws;  ws += (size_t)NROW * sizeof(float);
  float* part = (float*)ws;  ws += (size_t)8 * NROW * sizeof(float);    // 1 MiB
  float* p2   = (float*)ws;

  k_prep<<<NSPK, 256, 0, stream>>>(dvecs, Af, Bf, loo);
  k_gemm<<<2048, 256, 0, stream>>>(Af, Bf, wptr, part, diag);
  k_final1<<<NROW / 256, 256, 0, stream>>>(part, loo, diag, wptr, p2);
  k_final2<<<1, 128, 0, stream>>>(p2, out);
}

// Round 12
// 70.039 us; speedup vs baseline: 1.3125x; 1.0860x over previous
//
#include <hip/hip_runtime.h>
#include <hip/hip_bf16.h>

#define NSPK 1024
#define MU 32
#define DIM 512
#define DIMP (DIM + 8)
#define NROW (NSPK * MU)   // 32768
#define EPS 1e-6f

typedef __attribute__((ext_vector_type(4))) float f32x4;
typedef __attribute__((ext_vector_type(8))) short bf16x8;

#define GLOAD_LDS16(g, l)                                          \
  __builtin_amdgcn_global_load_lds(                                \
      (const __attribute__((address_space(1))) void*)(g),          \
      (__attribute__((address_space(3))) void*)(l), 16, 0, 0)

__device__ inline ushort f2bf(float x) {
  __hip_bfloat16 h = __float2bfloat16(x);
  return *reinterpret_cast<ushort*>(&h);
}

// ---------------------------------------------------------------------------
// Kernel 1: per-speaker prep. LOO cosines (fp32 exact) + normalized bf16
// A and B written in MFMA-FRAGMENT-MAJOR layout:
//   frag(rb16,kf) [A] / frag(nb16,kf) [B] = 512 ushorts; lane l holds
//   row/col = base16 + (l&15), k = kf*32 + (l>>4)*8 .. +8   (16 B chunk)
// grid = NSPK, block = 256   (unchanged since R2; verified)
// ---------------------------------------------------------------------------
__global__ __launch_bounds__(256) void k_prep(
    const float* __restrict__ dvecs,
    ushort* __restrict__ Af,    // [2048 rb16][16 kf][64 lane][8]
    ushort* __restrict__ Bf,    // [64 nb16][16 kf][64 lane][8]
    float* __restrict__ loo)    // [NROW]
{
  const int j = blockIdx.x, t = threadIdx.x;
  __shared__ float sD[MU * DIMP];   // padded raw speaker rows (66.5 KiB)
  __shared__ float sS[DIM];
  __shared__ float sred[4];
  __shared__ float sS2v;
  __shared__ float sInv[MU];

  const float* base = dvecs + (size_t)j * (MU * DIM);

  // single global read: stage rows + column sums
  float s0 = 0.f, s1 = 0.f;
  for (int m = 0; m < MU; ++m) {
    float a = base[m * DIM + t];
    float b = base[m * DIM + t + 256];
    sD[m * DIMP + t] = a;
    sD[m * DIMP + t + 256] = b;
    s0 += a; s1 += b;
  }
  sS[t] = s0; sS[t + 256] = s1;
  __syncthreads();

  // |S|^2
  float p = s0 * s0 + s1 * s1;
  for (int off = 32; off; off >>= 1) p += __shfl_down(p, off);
  if ((t & 63) == 0) sred[t >> 6] = p;
  __syncthreads();
  if (t == 0) sS2v = sred[0] + sred[1] + sred[2] + sred[3];
  __syncthreads();
  const float S2 = sS2v;

  // per-utterance dot(e,S), |e|^2 from LDS (8 lanes per row)
  const int g = t >> 3, l = t & 7;
  float dotS = 0.f, e2 = 0.f;
  for (int i = 0; i < DIM / 8; ++i) {
    int d = i * 8 + l;
    float ev = sD[g * DIMP + d];
    dotS += ev * sS[d];
    e2 += ev * ev;
  }
  for (int off = 4; off; off >>= 1) {
    dotS += __shfl_down(dotS, off);
    e2 += __shfl_down(e2, off);
  }
  if (l == 0) {
    float numer = dotS - e2;                          // e.(S-e)
    float d2 = fmaxf(S2 - 2.f * dotS + e2, 1e-30f);   // |S-e|^2
    loo[j * MU + g] = numer / (sqrtf(e2) * sqrtf(d2));
    sInv[g] = 1.f / sqrtf(e2);
  }
  __syncthreads();

  // A fragments: this speaker = rows j*32..+31 = rb16 j*2, j*2+1
  for (int i = 0; i < 8; ++i) {
    int idx = i * 256 + t;          // 0..2047 16B-chunks
    int fragL = idx >> 6;           // 0..31 (rbl*16 + kf)
    int lane2 = idx & 63;
    int rbl = fragL >> 4, kf = fragL & 15;
    int m = rbl * 16 + (lane2 & 15);
    int k0 = kf * 32 + (lane2 >> 4) * 8;
    float inv = sInv[m];
    ushort tmp[8];
#pragma unroll
    for (int z = 0; z < 8; ++z) tmp[z] = f2bf(sD[m * DIMP + k0 + z] * inv);
    *(bf16x8*)&Af[(((size_t)(j * 2 + rbl) * 16 + kf) << 9) + lane2 * 8] =
        *(bf16x8*)tmp;
  }

  // B fragment pieces for centroid j (col j -> lane&15 = j&15)
  if (t < 64) {
    int kf = t >> 2, q = t & 3;
    int lane2 = q * 16 + (j & 15);
    float invc = 1.f / sqrtf(S2);
    int k0 = kf * 32 + q * 8;
    ushort tmp[8];
#pragma unroll
    for (int z = 0; z < 8; ++z) tmp[z] = f2bf(sS[k0 + z] * invc);
    *(bf16x8*)&Bf[(((size_t)(j >> 4) * 16 + kf) << 9) + lane2 * 8] =
        *(bf16x8*)tmp;
  }
}

// ---------------------------------------------------------------------------
// Kernel 2: 3-buffer counted-vmcnt pipelined GEMM, fused exp-sum epilogue.
// Tile 128x128, BK=32 (16 K-steps), 256 thr (4 waves, 2wm x 2wn), wave
// tile 64x64 (acc[4][4]).
// R11 post-mortem: occupancy 18->27% changed nothing -- every variant
// (R3/R7/R10/R11) plateaus at ~56us because __syncthreads() = s_waitcnt
// vmcnt(0) + barrier DRAINS the just-issued prefetch every K-step; the
// L2 stage latency (~300-500cyc) serializes with compute. Fix (T3+T4):
// 3 LDS buffers, full unroll, and per step: s_waitcnt vmcnt(4) (only the
// step being consumed; next stage's 4 loads stay in flight) + raw
// s_barrier + sched_barrier, then STAGE(kt+2), then compute. Stage loads
// get ~2 compute phases to land. lgkmcnt(0)+sched_barrier before each
// barrier stops MFMA/ds_read sinking past it (rule #18). Per-thread
// in-flight ledger: prologue 8; each step waits 4, issues 4 (kt<14).
// LDS 48 KiB + 1 KiB -> 3 blocks/CU. VGPR must stay <~100: spills would
// corrupt vmcnt counting (watch WRITE_SIZE).
// Grid 2048 = 256 rb x 8 cb, XCD-chunked swizzle (32-rb band per XCD).
// ---------------------------------------------------------------------------
__global__ __launch_bounds__(256, 1) void k_gemm(
    const ushort* __restrict__ Af,
    const ushort* __restrict__ Bf,
    const float* __restrict__ wp,
    float* __restrict__ part,    // [8][NROW] partial sumexp per col-chunk
    float* __restrict__ diag)    // [NROW] raw cos vs own full centroid
{
  __shared__ ushort ldsA[3 * 8 * 512];    // 24 KiB: 3 bufs x 8 frags x 1 KiB
  __shared__ ushort ldsB[3 * 8 * 512];    // 24 KiB
  __shared__ float sPart[128][2];         // 1 KiB

  const int t = threadIdx.x;
  const int w = t >> 6, lane = t & 63;
  const int lr = lane & 15, lk = lane >> 4;
  const int wm = w >> 1, wn = w & 1;      // 2 x 2 wave grid
  // XCD-chunked block swizzle (HW: consecutive bids round-robin XCDs)
  const int bid = blockIdx.x;
  const int xcd = bid & 7, ii = bid >> 3;     // ii in [0,256) per XCD
  const int rb = xcd * 32 + (ii >> 3);        // 0..255 (128 rows each)
  const int cb = ii & 7;                      // 0..7   (128 cols each)

  f32x4 acc[4][4];
#pragma unroll
  for (int a = 0; a < 4; ++a)
#pragma unroll
    for (int b = 0; b < 4; ++b) acc[a][b] = (f32x4)0.f;

  // staging: 8 A-frags + 8 B-frags per K-step (BK=32 -> kf = kt directly);
  // wave w stages A el {w, w+4} and B el {w, w+4} -> 4 loads/thread/step.
#define STAGE(kt, bi)                                                        \
  {                                                                          \
    _Pragma("unroll")                                                        \
    for (int r = 0; r < 2; ++r) {                                            \
      const int el = r * 4 + w;              /* 0..7 */                      \
      GLOAD_LDS16(                                                           \
          Af + (((size_t)(rb * 8 + el) * 16 + (kt)) << 9) + lane * 8,        \
          &ldsA[(bi) * 4096 + el * 512 + lane * 8]);                         \
      GLOAD_LDS16(                                                           \
          Bf + (((size_t)(cb * 8 + el) * 16 + (kt)) << 9) + lane * 8,        \
          &ldsB[(bi) * 4096 + el * 512 + lane * 8]);                         \
    }                                                                        \
  }

  // prologue: 2-deep prefetch (8 loads/thread in flight)
  STAGE(0, 0);
  STAGE(1, 1);

#pragma unroll
  for (int kt = 0; kt < 16; ++kt) {
    // consume-wait: only the K-step we are about to read (leave 4 in flight)
    if (kt < 15) {
      asm volatile("s_waitcnt vmcnt(4)" ::: "memory");
    } else {
      asm volatile("s_waitcnt vmcnt(0)" ::: "memory");
    }
    __builtin_amdgcn_s_barrier();
    __builtin_amdgcn_sched_barrier(0);

    if (kt < 14) STAGE(kt + 2, (kt + 2) % 3);

    const ushort* lA = &ldsA[(kt % 3) * 4096];
    const ushort* lB = &ldsB[(kt % 3) * 4096];
    bf16x8 bfr[4];
#pragma unroll
    for (int nf = 0; nf < 4; ++nf)
      bfr[nf] = *(const bf16x8*)&lB[((wn * 4 + nf) << 9) + lane * 8];
#pragma unroll
    for (int mf = 0; mf < 4; ++mf) {
      const bf16x8 afr =
          *(const bf16x8*)&lA[((wm * 4 + mf) << 9) + lane * 8];
#pragma unroll
      for (int nf = 0; nf < 4; ++nf)
        acc[mf][nf] = __builtin_amdgcn_mfma_f32_16x16x32_bf16(
            afr, bfr[nf], acc[mf][nf], 0, 0, 0);
    }

    // all ds_reads complete before next barrier (stop MFMA/ds sinking past)
    asm volatile("s_waitcnt lgkmcnt(0)" ::: "memory");
    __builtin_amdgcn_sched_barrier(0);
  }
#undef STAGE

  const float W = *wp;

  // ---- diag capture (raw cos) before exp consumes acc ----
  // block rows = speakers rb*4..+3; col c = rb*4+sp in this block iff
  // cb == c>>7 (= rb>>5, no carry since sp<4).
  if (cb == (rb >> 5)) {
#pragma unroll
    for (int sp = 0; sp < 4; ++sp) {
      const int c = rb * 4 + sp;
      if (wm == (sp >> 1) && wn == ((c >> 6) & 1)) {
        const int nfo = (c >> 4) & 3;
#pragma unroll
        for (int mh = 0; mh < 2; ++mh) {
          f32x4 dsel = acc[(sp & 1) * 2 + mh][0];
#pragma unroll
          for (int nf = 1; nf < 4; ++nf)
            if (nf == nfo) dsel = acc[(sp & 1) * 2 + mh][nf];  // static idx
          if (lr == (c & 15)) {
#pragma unroll
            for (int i = 0; i < 4; ++i)
              diag[c * 32 + mh * 16 + lk * 4 + i] = dsel[i];
          }
        }
      }
    }
  }

  // ---- fused epilogue: exp((fmax(cos,eps)-1)*W), reduce over 64 cols ----
#pragma unroll
  for (int mf = 0; mf < 4; ++mf)
#pragma unroll
    for (int i = 0; i < 4; ++i) {
      float s = 0.f;
#pragma unroll
      for (int nf = 0; nf < 4; ++nf)
        s += __expf((fmaxf(acc[mf][nf][i], EPS) - 1.f) * W);
      s += __shfl_xor(s, 1);
      s += __shfl_xor(s, 2);
      s += __shfl_xor(s, 4);
      s += __shfl_xor(s, 8);
      if (lr == 0) sPart[wm * 64 + mf * 16 + lk * 4 + i][wn] = s;
    }
  __syncthreads();
  if (t < 128)
    part[(size_t)cb * NROW + rb * 128 + t] = sPart[t][0] + sPart[t][1];
}

// ---------------------------------------------------------------------------
// Final: sum 8 col-chunk partials, swap exp(diag)->exp(loo), close lse,
// deterministic 2-stage sum.  L_row = log(s - exp(dt) + exp(lt)) - lt
// ---------------------------------------------------------------------------
__global__ __launch_bounds__(256) void k_final1(
    const float* __restrict__ part, const float* __restrict__ loo,
    const float* __restrict__ diag, const float* __restrict__ wp,
    float* __restrict__ p2)
{
  const int t = threadIdx.x;
  const int r = blockIdx.x * 256 + t;
  const float W = *wp;
  float s = 0.f;
#pragma unroll
  for (int c = 0; c < 8; ++c) s += part[(size_t)c * NROW + r];
  const float lt = (fmaxf(loo[r], EPS) - 1.f) * W;
  const float dt = (fmaxf(diag[r], EPS) - 1.f) * W;
  s += __expf(lt) - __expf(dt);
  float v = logf(s) - lt;
  __shared__ float red[4];
  for (int off = 32; off; off >>= 1) v += __shfl_down(v, off);
  if ((t & 63) == 0) red[t >> 6] = v;
  __syncthreads();
  if (t == 0) p2[blockIdx.x] = red[0] + red[1] + red[2] + red[3];
}

__global__ __launch_bounds__(128) void k_final2(
    const float* __restrict__ p2, float* __restrict__ out)
{
  const int t = threadIdx.x;
  float v = p2[t];
  for (int off = 32; off; off >>= 1) v += __shfl_down(v, off);
  __shared__ float red[2];
  if ((t & 63) == 0) red[t >> 6] = v;
  __syncthreads();
  if (t == 0) out[0] = red[0] + red[1];
}

extern "C" void kernel_launch(void* const* d_in, const int* in_sizes, int n_in,
                              void* d_out, int out_size, void* d_ws, size_t ws_size,
                              hipStream_t stream) {
  const float* dvecs = (const float*)d_in[0];
  const float* wptr  = (const float*)d_in[1];
  // b cancels algebraically (shift = w+b subtracted and re-added) -> unused
  float* out = (float*)d_out;

  char* ws = (char*)d_ws;
  ushort* Af = (ushort*)ws;  ws += (size_t)NROW * DIM * sizeof(ushort); // 32 MiB
  ushort* Bf = (ushort*)ws;  ws += (size_t)NSPK * DIM * sizeof(ushort); // 1 MiB
  float* loo  = (float*)ws;  ws += (size_t)NROW * sizeof(float);
  float* diag = (float*)ws;  ws += (size_t)NROW * sizeof(float);
  float* part = (float*)ws;  ws += (size_t)8 * NROW * sizeof(float);    // 1 MiB
  float* p2   = (float*)ws;

  k_prep<<<NSPK, 256, 0, stream>>>(dvecs, Af, Bf, loo);
  k_gemm<<<2048, 256, 0, stream>>>(Af, Bf, wptr, part, diag);
  k_final1<<<NROW / 256, 256, 0, stream>>>(part, loo, diag, wptr, p2);
  k_final2<<<1, 128, 0, stream>>>(p2, out);
}

// Round 13
// 69.091 us; speedup vs baseline: 1.3305x; 1.0137x over previous
//
#include <hip/hip_runtime.h>
#include <hip/hip_bf16.h>

#define NSPK 1024
#define MU 32
#define DIM 512
#define DIMP (DIM + 8)
#define NROW (NSPK * MU)   // 32768
#define EPS 1e-6f

typedef __attribute__((ext_vector_type(4))) float f32x4;
typedef __attribute__((ext_vector_type(8))) short bf16x8;

#define GLOAD_LDS16(g, l)                                          \
  __builtin_amdgcn_global_load_lds(                                \
      (const __attribute__((address_space(1))) void*)(g),          \
      (__attribute__((address_space(3))) void*)(l), 16, 0, 0)

__device__ inline ushort f2bf(float x) {
  __hip_bfloat16 h = __float2bfloat16(x);
  return *reinterpret_cast<ushort*>(&h);
}

// ---------------------------------------------------------------------------
// Kernel 1: per-speaker prep. LOO cosines (fp32 exact) + normalized bf16
// A and B written in MFMA-FRAGMENT-MAJOR layout:
//   frag(rb16,kf) [A] / frag(nb16,kf) [B] = 512 ushorts; lane l holds
//   row/col = base16 + (l&15), k = kf*32 + (l>>4)*8 .. +8   (16 B chunk)
// grid = NSPK, block = 256   (unchanged since R2; verified)
// ---------------------------------------------------------------------------
__global__ __launch_bounds__(256) void k_prep(
    const float* __restrict__ dvecs,
    ushort* __restrict__ Af,    // [2048 rb16][16 kf][64 lane][8]
    ushort* __restrict__ Bf,    // [64 nb16][16 kf][64 lane][8]
    float* __restrict__ loo)    // [NROW]
{
  const int j = blockIdx.x, t = threadIdx.x;
  __shared__ float sD[MU * DIMP];   // padded raw speaker rows (66.5 KiB)
  __shared__ float sS[DIM];
  __shared__ float sred[4];
  __shared__ float sS2v;
  __shared__ float sInv[MU];

  const float* base = dvecs + (size_t)j * (MU * DIM);

  // single global read: stage rows + column sums
  float s0 = 0.f, s1 = 0.f;
  for (int m = 0; m < MU; ++m) {
    float a = base[m * DIM + t];
    float b = base[m * DIM + t + 256];
    sD[m * DIMP + t] = a;
    sD[m * DIMP + t + 256] = b;
    s0 += a; s1 += b;
  }
  sS[t] = s0; sS[t + 256] = s1;
  __syncthreads();

  // |S|^2
  float p = s0 * s0 + s1 * s1;
  for (int off = 32; off; off >>= 1) p += __shfl_down(p, off);
  if ((t & 63) == 0) sred[t >> 6] = p;
  __syncthreads();
  if (t == 0) sS2v = sred[0] + sred[1] + sred[2] + sred[3];
  __syncthreads();
  const float S2 = sS2v;

  // per-utterance dot(e,S), |e|^2 from LDS (8 lanes per row)
  const int g = t >> 3, l = t & 7;
  float dotS = 0.f, e2 = 0.f;
  for (int i = 0; i < DIM / 8; ++i) {
    int d = i * 8 + l;
    float ev = sD[g * DIMP + d];
    dotS += ev * sS[d];
    e2 += ev * ev;
  }
  for (int off = 4; off; off >>= 1) {
    dotS += __shfl_down(dotS, off);
    e2 += __shfl_down(e2, off);
  }
  if (l == 0) {
    float numer = dotS - e2;                          // e.(S-e)
    float d2 = fmaxf(S2 - 2.f * dotS + e2, 1e-30f);   // |S-e|^2
    loo[j * MU + g] = numer / (sqrtf(e2) * sqrtf(d2));
    sInv[g] = 1.f / sqrtf(e2);
  }
  __syncthreads();

  // A fragments: this speaker = rows j*32..+31 = rb16 j*2, j*2+1
  for (int i = 0; i < 8; ++i) {
    int idx = i * 256 + t;          // 0..2047 16B-chunks
    int fragL = idx >> 6;           // 0..31 (rbl*16 + kf)
    int lane2 = idx & 63;
    int rbl = fragL >> 4, kf = fragL & 15;
    int m = rbl * 16 + (lane2 & 15);
    int k0 = kf * 32 + (lane2 >> 4) * 8;
    float inv = sInv[m];
    ushort tmp[8];
#pragma unroll
    for (int z = 0; z < 8; ++z) tmp[z] = f2bf(sD[m * DIMP + k0 + z] * inv);
    *(bf16x8*)&Af[(((size_t)(j * 2 + rbl) * 16 + kf) << 9) + lane2 * 8] =
        *(bf16x8*)tmp;
  }

  // B fragment pieces for centroid j (col j -> lane&15 = j&15)
  if (t < 64) {
    int kf = t >> 2, q = t & 3;
    int lane2 = q * 16 + (j & 15);
    float invc = 1.f / sqrtf(S2);
    int k0 = kf * 32 + q * 8;
    ushort tmp[8];
#pragma unroll
    for (int z = 0; z < 8; ++z) tmp[z] = f2bf(sS[k0 + z] * invc);
    *(bf16x8*)&Bf[(((size_t)(j >> 4) * 16 + kf) << 9) + lane2 * 8] =
        *(bf16x8*)tmp;
  }
}

// ---------------------------------------------------------------------------
// Kernel 2: 3-buffer counted-vmcnt + register-double-buffered GEMM.
// Tile 128x128, BK=32 (16 K-steps), 256 thr (4 waves, 2wm x 2wn), wave
// tile 64x64 (acc[4][4]).
// R12 post-mortem: per-CU totals are L2-stage ~15us, LDS-read ~15us,
// MFMA ~16.6us and measured 50.6 ~= their SUM -- the pipes run
// sequentially because each K-step does barrier -> ds_read(wait) -> MFMA.
// Fix: fragment register double-buffer. Per step: issue ds_reads for
// step kt+1 (alternate reg set, NO wait) BEFORE the MFMA cluster of step
// kt; LDS pipe serves kt+1 reads while matrix pipe drains kt's MFMAs;
// VMEM streams stage(kt+3) underneath. lgkmcnt(0) only at step end
// (buffer safety across the next barrier, rule #18); vmcnt(4)
// consume-waits (R12, kept). Static [kt&1] reg-set indexing under full
// unroll (rule #20). Addresses hoisted to per-thread bases (VALU diet).
// Ledger: prologue issues stages 0,1,2 (8 in flight after vmcnt(4)+
// STAGE(2)); iter kt<=12 issues stage(kt+3) -> top-of-iter in-flight 8,
// wait leaves 4. Buf safety: stage(kt+3) writes buf(kt%3), whose readers
// (ds_reads of step kt, issued iter kt-1) completed at iter kt-1's
// lgkmcnt(0), ordered block-wide by iter kt's barrier.
// LDS 49 KiB -> 3 blocks/CU; VGPR ~160 -> 3 waves/SIMD.
// Grid 2048 = 256 rb x 8 cb, XCD-chunked swizzle (32-rb band per XCD).
// ---------------------------------------------------------------------------
__global__ __launch_bounds__(256, 1) void k_gemm(
    const ushort* __restrict__ Af,
    const ushort* __restrict__ Bf,
    const float* __restrict__ wp,
    float* __restrict__ part,    // [8][NROW] partial sumexp per col-chunk
    float* __restrict__ diag)    // [NROW] raw cos vs own full centroid
{
  __shared__ ushort ldsA[3 * 8 * 512];    // 24 KiB: 3 bufs x 8 frags x 1 KiB
  __shared__ ushort ldsB[3 * 8 * 512];    // 24 KiB
  __shared__ float sPart[128][2];         // 1 KiB

  const int t = threadIdx.x;
  const int w = t >> 6, lane = t & 63;
  const int lr = lane & 15, lk = lane >> 4;
  const int wm = w >> 1, wn = w & 1;      // 2 x 2 wave grid
  // XCD-chunked block swizzle (HW: consecutive bids round-robin XCDs)
  const int bid = blockIdx.x;
  const int xcd = bid & 7, ii = bid >> 3;     // ii in [0,256) per XCD
  const int rb = xcd * 32 + (ii >> 3);        // 0..255 (128 rows each)
  const int cb = ii & 7;                      // 0..7   (128 cols each)

  f32x4 acc[4][4];
#pragma unroll
  for (int a = 0; a < 4; ++a)
#pragma unroll
    for (int b = 0; b < 4; ++b) acc[a][b] = (f32x4)0.f;

  // hoisted per-thread staging bases (ushort units); step offset = kt*512
  const ushort* gA0 = Af + (((size_t)(rb * 8 + w) * 16) << 9) + lane * 8;
  const ushort* gA1 = Af + (((size_t)(rb * 8 + w + 4) * 16) << 9) + lane * 8;
  const ushort* gB0 = Bf + (((size_t)(cb * 8 + w) * 16) << 9) + lane * 8;
  const ushort* gB1 = Bf + (((size_t)(cb * 8 + w + 4) * 16) << 9) + lane * 8;
  ushort* dA0 = &ldsA[w * 512 + lane * 8];
  ushort* dA1 = &ldsA[(w + 4) * 512 + lane * 8];
  ushort* dB0 = &ldsB[w * 512 + lane * 8];
  ushort* dB1 = &ldsB[(w + 4) * 512 + lane * 8];

#define STAGE(kt, bi)                                   \
  {                                                     \
    GLOAD_LDS16(gA0 + (kt) * 512, dA0 + (bi) * 4096);   \
    GLOAD_LDS16(gA1 + (kt) * 512, dA1 + (bi) * 4096);   \
    GLOAD_LDS16(gB0 + (kt) * 512, dB0 + (bi) * 4096);   \
    GLOAD_LDS16(gB1 + (kt) * 512, dB1 + (bi) * 4096);   \
  }

  // fragment register double-buffer; indices static under full unroll
  bf16x8 afr[2][4], bfr[2][4];
  const ushort* lA0 = &ldsA[(wm * 4) * 512 + lane * 8];
  const ushort* lB0 = &ldsB[(wn * 4) * 512 + lane * 8];

#define DSREAD(set, bi)                                                   \
  {                                                                       \
    _Pragma("unroll")                                                     \
    for (int nf = 0; nf < 4; ++nf)                                        \
      bfr[set][nf] = *(const bf16x8*)(lB0 + (bi) * 4096 + nf * 512);      \
    _Pragma("unroll")                                                     \
    for (int mf = 0; mf < 4; ++mf)                                        \
      afr[set][mf] = *(const bf16x8*)(lA0 + (bi) * 4096 + mf * 512);      \
  }

  // ---- prologue ----
  STAGE(0, 0);
  STAGE(1, 1);
  asm volatile("s_waitcnt vmcnt(4)" ::: "memory");   // stage(0) landed
  __builtin_amdgcn_s_barrier();
  __builtin_amdgcn_sched_barrier(0);
  STAGE(2, 2);
  DSREAD(0, 0);                                      // step-0 frags
  asm volatile("s_waitcnt lgkmcnt(0)" ::: "memory");
  __builtin_amdgcn_sched_barrier(0);

  // ---- pipelined K-loop ----
#pragma unroll
  for (int kt = 0; kt < 16; ++kt) {
    if (kt < 14) {
      asm volatile("s_waitcnt vmcnt(4)" ::: "memory");  // stage(kt+1) landed
    } else {
      asm volatile("s_waitcnt vmcnt(0)" ::: "memory");
    }
    __builtin_amdgcn_s_barrier();
    __builtin_amdgcn_sched_barrier(0);

    if (kt <= 12) STAGE(kt + 3, (kt + 3) % 3);
    if (kt < 15) DSREAD((kt + 1) & 1, (kt + 1) % 3);   // no wait: overlaps MFMA

    __builtin_amdgcn_s_setprio(1);
#pragma unroll
    for (int mf = 0; mf < 4; ++mf)
#pragma unroll
      for (int nf = 0; nf < 4; ++nf)
        acc[mf][nf] = __builtin_amdgcn_mfma_f32_16x16x32_bf16(
            afr[kt & 1][mf], bfr[kt & 1][nf], acc[mf][nf], 0, 0, 0);
    __builtin_amdgcn_s_setprio(0);

    if (kt < 15) {
      asm volatile("s_waitcnt lgkmcnt(0)" ::: "memory");  // buf safety
      __builtin_amdgcn_sched_barrier(0);
    }
  }
#undef STAGE
#undef DSREAD

  const float W = *wp;

  // ---- diag capture (raw cos) before exp consumes acc ----
  // block rows = speakers rb*4..+3; col c = rb*4+sp in this block iff
  // cb == c>>7 (= rb>>5, no carry since sp<4).
  if (cb == (rb >> 5)) {
#pragma unroll
    for (int sp = 0; sp < 4; ++sp) {
      const int c = rb * 4 + sp;
      if (wm == (sp >> 1) && wn == ((c >> 6) & 1)) {
        const int nfo = (c >> 4) & 3;
#pragma unroll
        for (int mh = 0; mh < 2; ++mh) {
          f32x4 dsel = acc[(sp & 1) * 2 + mh][0];
#pragma unroll
          for (int nf = 1; nf < 4; ++nf)
            if (nf == nfo) dsel = acc[(sp & 1) * 2 + mh][nf];  // static idx
          if (lr == (c & 15)) {
#pragma unroll
            for (int i = 0; i < 4; ++i)
              diag[c * 32 + mh * 16 + lk * 4 + i] = dsel[i];
          }
        }
      }
    }
  }

  // ---- fused epilogue: exp((fmax(cos,eps)-1)*W), reduce over 64 cols ----
#pragma unroll
  for (int mf = 0; mf < 4; ++mf)
#pragma unroll
    for (int i = 0; i < 4; ++i) {
      float s = 0.f;
#pragma unroll
      for (int nf = 0; nf < 4; ++nf)
        s += __expf((fmaxf(acc[mf][nf][i], EPS) - 1.f) * W);
      s += __shfl_xor(s, 1);
      s += __shfl_xor(s, 2);
      s += __shfl_xor(s, 4);
      s += __shfl_xor(s, 8);
      if (lr == 0) sPart[wm * 64 + mf * 16 + lk * 4 + i][wn] = s;
    }
  __syncthreads();
  if (t < 128)
    part[(size_t)cb * NROW + rb * 128 + t] = sPart[t][0] + sPart[t][1];
}

// ---------------------------------------------------------------------------
// Final: sum 8 col-chunk partials, swap exp(diag)->exp(loo), close lse,
// deterministic 2-stage sum.  L_row = log(s - exp(dt) + exp(lt)) - lt
// ---------------------------------------------------------------------------
__global__ __launch_bounds__(256) void k_final1(
    const float* __restrict__ part, const float* __restrict__ loo,
    const float* __restrict__ diag, const float* __restrict__ wp,
    float* __restrict__ p2)
{
  const int t = threadIdx.x;
  const int r = blockIdx.x * 256 + t;
  const float W = *wp;
  float s = 0.f;
#pragma unroll
  for (int c = 0; c < 8; ++c) s += part[(size_t)c * NROW + r];
  const float lt = (fmaxf(loo[r], EPS) - 1.f) * W;
  const float dt = (fmaxf(diag[r], EPS) - 1.f) * W;
  s += __expf(lt) - __expf(dt);
  float v = logf(s) - lt;
  __shared__ float red[4];
  for (int off = 32; off; off >>= 1) v += __shfl_down(v, off);
  if ((t & 63) == 0) red[t >> 6] = v;
  __syncthreads();
  if (t == 0) p2[blockIdx.x] = red[0] + red[1] + red[2] + red[3];
}

__global__ __launch_bounds__(128) void k_final2(
    const float* __restrict__ p2, float* __restrict__ out)
{
  const int t = threadIdx.x;
  float v = p2[t];
  for (int off = 32; off; off >>= 1) v += __shfl_down(v, off);
  __shared__ float red[2];
  if ((t & 63) == 0) red[t >> 6] = v;
  __syncthreads();
  if (t == 0) out[0] = red[0] + red[1];
}

extern "C" void kernel_launch(void* const* d_in, const int* in_sizes, int n_in,
                              void* d_out, int out_size, void* d_ws, size_t ws_size,
                              hipStream_t stream) {
  const float* dvecs = (const float*)d_in[0];
  const float* wptr  = (const float*)d_in[1];
  // b cancels algebraically (shift = w+b subtracted and re-added) -> unused
  float* out = (float*)d_out;

  char* ws = (char*)d_ws;
  ushort* Af = (ushort*)ws;  ws += (size_t)NROW * DIM * sizeof(ushort); // 32 MiB
  ushort* Bf = (ushort*)ws;  ws += (size_t)NSPK * DIM * sizeof(ushort); // 1 MiB
  float* loo  = (float*)ws;  ws += (size_t)NROW * sizeof(float);
  float* diag = (float*)ws;  ws += (size_t)NROW * sizeof(float);
  float* part = (float*)ws;  ws += (size_t)8 * NROW * sizeof(float);    // 1 MiB
  float* p2   = (float*)ws;

  k_prep<<<NSPK, 256, 0, stream>>>(dvecs, Af, Bf, loo);
  k_gemm<<<2048, 256, 0, stream>>>(Af, Bf, wptr, part, diag);
  k_final1<<<NROW / 256, 256, 0, stream>>>(part, loo, diag, wptr, p2);
  k_final2<<<1, 128, 0, stream>>>(p2, out);
}